// Round 11
// baseline (276.964 us; speedup 1.0000x reference)
//
#include <hip/hip_runtime.h>
#include <hip/hip_bf16.h>

#define N_IMG 32
#define CIN   128
#define INH   64
#define INW   64
#define COUT  256
#define OH    62
#define OW    62

#define IN_BLOCKS 2048               // 32 img x 4 cb x 16 ih-groups (4 rows each)
#define WT_BLOCKS (294912 / 256)     // 1152

typedef short          bf16x8 __attribute__((ext_vector_type(8)));
typedef unsigned short u16x8  __attribute__((ext_vector_type(8)));
typedef float          f32x4  __attribute__((ext_vector_type(4)));
typedef float          f32x2  __attribute__((ext_vector_type(2)));

__device__ __forceinline__ unsigned short f2bf(float x) {
    unsigned int u = __float_as_uint(x);
    u += 0x7fffu + ((u >> 16) & 1u);   // RNE
    return (unsigned short)(u >> 16);
}

__device__ __forceinline__ void gload_lds16(const void* g, void* l) {
    // global -> LDS DMA, 16 B per lane.
    // LDS dest: wave-uniform base, HW adds lane*16.
    // Global src: PER-LANE address — caller must include the lane offset
    // (r10 bug: a wave-uniform src loads the same 16B into every lane slot).
    __builtin_amdgcn_global_load_lds(
        (const __attribute__((address_space(1))) unsigned int*)g,
        (__attribute__((address_space(3))) unsigned int*)l, 16, 0, 0);
}

// Merged pre-pass: blocks [0,2048) transform input (4 ih rows each),
// [2048, 2048+1152) transform weights.
// TIn layout: [img][cb(4)][ih(64)][chunk(256)][8] bf16; chunk c = (iw = c>>2,
// cg = (c&3) ^ ((iw>>1)&3)) — XOR swizzle baked into the GLOBAL layout so the
// linear global_load_lds DMA lands pre-swizzled (rule #21).
// WT layout: [khw(9)][cg(16)][co(256)][i(8)] bf16, ci = cg*8 + i (A-frag order).
__global__ __launch_bounds__(256)
void transform_kernel(const float* __restrict__ In,
                      const float* __restrict__ Wsrc,
                      unsigned short* __restrict__ TIn,
                      unsigned short* __restrict__ WT) {
    if (blockIdx.x >= IN_BLOCKS) {      // ---- weight path (no barriers) ----
        int idx = (blockIdx.x - IN_BLOCKS) * 256 + threadIdx.x;   // < 294912
        int i   = idx & 7;
        int co  = (idx >> 3) & 255;
        int cgk = idx >> 11;            // khw*16 + cg
        int cg  = cgk & 15;
        int khw = cgk >> 4;             // 0..8
        int kh  = khw / 3, kw = khw - 3 * kh;
        int ci  = cg * 8 + i;
        WT[idx] = f2bf(Wsrc[co * (CIN * 9) + ci * 9 + kh * 3 + kw]);
        return;
    }
    // ---- input path: LDS-transposed, coalesced both sides, 4 rows per block ----
    __shared__ float T[32][66];           // stride 66: float2-aligned, 2-way banks max
    const int bid = blockIdx.x;           // img*64 + cb*16 + ihg
    const int ih0 = (bid & 15) * 4;
    const int cb  = (bid >> 4) & 3;
    const int img = bid >> 6;

    const int r   = threadIdx.x >> 3;           // load row 0..31
    const int c0  = (threadIdx.x & 7) * 8;      // load col
    const int c   = threadIdx.x;                // store chunk
    const int iw  = c >> 2;
    const int cg  = (c & 3) ^ ((iw >> 1) & 3);

    for (int j = 0; j < 4; ++j) {
        const int ih = ih0 + j;
        const float* p = In + (((size_t)(img * CIN + cb * 32 + r)) * INH + ih) * INW + c0;
        f32x4 a = *(const f32x4*)p;
        f32x4 b = *(const f32x4*)(p + 4);
        *(f32x2*)&T[r][c0 + 0] = f32x2{a[0], a[1]};
        *(f32x2*)&T[r][c0 + 2] = f32x2{a[2], a[3]};
        *(f32x2*)&T[r][c0 + 4] = f32x2{b[0], b[1]};
        *(f32x2*)&T[r][c0 + 6] = f32x2{b[2], b[3]};
        __syncthreads();
        u16x8 v;
#pragma unroll
        for (int i = 0; i < 8; ++i) v[i] = f2bf(T[cg * 8 + i][iw]);
        *(u16x8*)&TIn[((size_t)((img * 4 + cb) * 64 + ih) * 256 + c) * 8] = v;
        if (j < 3) __syncthreads();   // T reused next iteration
    }
}

// BARRIER-FREE conv kernel. One 256-thread block per (img, oh); wave w owns
// co in [64w, 64w+64). Each wave stages ITS OWN input row copy into a private
// LDS double-buffer via global_load_lds (wave-local consistency: counted vmcnt,
// no __syncthreads in the main loop). Rationale (r5-r8 decomposition): per
// CU-stage, MFMA (3725 cyc) + weight-L2 (3430 cyc) + VALU (1400) summed to the
// measured 8.6K-cyc stage wall — the 12 block barriers phase-locked all 16
// waves/CU into a weight-load convoy after every barrier. With no barriers the
// 16 waves destagger freely and the three terms overlap across waves.
// vmcnt ledger per stage s (in-order retire):
//   queue at the asm wait: [D_s(4), w0x4]  -> s_waitcnt vmcnt(4) retires D_s
//   (buffer 'cur' guaranteed written before any xf ds_read below the asm).
//   D_{s+1} issues between w2 loads and cluster1, fenced by sched_barrier(0)
//   so the compiler cannot move loads across it and break the count.
__global__ __launch_bounds__(256, 4)
void conv_mfma_bf16_kernel(const unsigned short* __restrict__ TIn,
                           const unsigned short* __restrict__ WT,
                           float* __restrict__ Out) {
    // [wave][buf][2112]: 4096 B row data + 128 B zero pad (rows 64,65).
    __shared__ unsigned short Lin[4][2][2112];

    // Bijective XCD-chunked remap: 1984 = 8*248 -> XCD x gets images [4x, 4x+4).
    const int g   = blockIdx.x;
    const int f   = (g & 7) * 248 + (g >> 3);
    const int img = f / OH;
    const int oh  = f - img * OH;

    const int tid  = threadIdx.x;
    const int wave = tid >> 6;      // 0..3
    const int lane = tid & 63;
    const int q    = lane >> 4;     // quad 0..3
    const int ml   = lane & 15;
    const int co_base = wave * 64;

    const unsigned short* tin_base = TIn + (size_t)img * (4 * 64 * 2048);
    const bf16x8* WTv = (const bf16x8*)WT;
    const int wlane = q * 256 + co_base + ml;   // lane part of A-frag index

    // Per-lane LDS ushort offsets for B fragments (constant across stages).
    // Chunk slot for cg=q at row r is q ^ ((r>>1)&3): measured 0 bank conflicts.
    int xoff[3][4];
#pragma unroll
    for (int kw = 0; kw < 3; ++kw)
#pragma unroll
        for (int ni = 0; ni < 4; ++ni) {
            const int r = ni * 16 + ml + kw;
            xoff[kw][ni] = r * 32 + ((q ^ ((r >> 1) & 3)) << 3);
        }

    f32x4 acc[4][4];
    const f32x4 zero = {0.f, 0.f, 0.f, 0.f};
#pragma unroll
    for (int a = 0; a < 4; ++a)
#pragma unroll
        for (int b = 0; b < 4; ++b) acc[a][b] = zero;

    // Prologue: zero this wave's pad rows (both buffers) + DMA stage-0 row.
    ((unsigned int*)&Lin[wave][lane >> 5][2048])[lane & 31] = 0u;
    {
        const unsigned short* row0 = tin_base + oh * 2048;   // kh=0, cb=0
#pragma unroll
        for (int k = 0; k < 4; ++k)
            gload_lds16(row0 + k * 512 + lane * 8, &Lin[wave][0][k * 512]);
    }
    __syncthreads();   // one-time: drains D_0 + pad writes; uniform start

#pragma unroll
    for (int s = 0; s < 12; ++s) {
        const int cur = s & 1;
        const int kh = s >> 2, cb = s & 3;
        const bf16x8* wstage = WTv + (kh * 48 + cb * 4) * 256;   // kw stride 4096

        bf16x8 w0[4], w1[4], w2[4];
#pragma unroll
        for (int mi = 0; mi < 4; ++mi) w0[mi] = wstage[wlane + mi * 16];

        // retire this stage's input DMA (queue: [D_s(4), w0x4] -> leave 4)
        asm volatile("s_waitcnt vmcnt(4)" ::: "memory");

#pragma unroll
        for (int mi = 0; mi < 4; ++mi) w1[mi] = wstage[4096 + wlane + mi * 16];

        // ---- cluster 0 (kw=0) ----
        {
            bf16x8 xf[4];
#pragma unroll
            for (int ni = 0; ni < 4; ++ni)
                xf[ni] = *(const bf16x8*)&Lin[wave][cur][xoff[0][ni]];
#pragma unroll
            for (int mi = 0; mi < 4; ++mi)
#pragma unroll
                for (int ni = 0; ni < 4; ++ni)
                    acc[mi][ni] = __builtin_amdgcn_mfma_f32_16x16x32_bf16(
                        w0[mi], xf[ni], acc[mi][ni], 0, 0, 0);
        }
#pragma unroll
        for (int mi = 0; mi < 4; ++mi) w2[mi] = wstage[8192 + wlane + mi * 16];

        // next stage's DMA into the other buffer, fenced to keep vmcnt exact
        if (s < 11) {
            __builtin_amdgcn_sched_barrier(0);
            const int s1 = s + 1;
            const unsigned short* src =
                tin_base + ((s1 & 3) * 64 + oh + (s1 >> 2)) * 2048;
#pragma unroll
            for (int k = 0; k < 4; ++k)
                gload_lds16(src + k * 512 + lane * 8, &Lin[wave][cur ^ 1][k * 512]);
            __builtin_amdgcn_sched_barrier(0);
        }

        // ---- cluster 1 (kw=1) ----
        {
            bf16x8 xf[4];
#pragma unroll
            for (int ni = 0; ni < 4; ++ni)
                xf[ni] = *(const bf16x8*)&Lin[wave][cur][xoff[1][ni]];
#pragma unroll
            for (int mi = 0; mi < 4; ++mi)
#pragma unroll
                for (int ni = 0; ni < 4; ++ni)
                    acc[mi][ni] = __builtin_amdgcn_mfma_f32_16x16x32_bf16(
                        w1[mi], xf[ni], acc[mi][ni], 0, 0, 0);
        }
        // ---- cluster 2 (kw=2) ----
        {
            bf16x8 xf[4];
#pragma unroll
            for (int ni = 0; ni < 4; ++ni)
                xf[ni] = *(const bf16x8*)&Lin[wave][cur][xoff[2][ni]];
#pragma unroll
            for (int mi = 0; mi < 4; ++mi)
#pragma unroll
                for (int ni = 0; ni < 4; ++ni)
                    acc[mi][ni] = __builtin_amdgcn_mfma_f32_16x16x32_bf16(
                        w2[mi], xf[ni], acc[mi][ni], 0, 0, 0);
        }
    }

    // Epilogue: C/D layout col=lane&15, row=q*4+r (verified 16x16x32 mapping).
#pragma unroll
    for (int mi = 0; mi < 4; ++mi) {
#pragma unroll
        for (int r = 0; r < 4; ++r) {
            const int co = co_base + mi * 16 + q * 4 + r;
            float* op = Out + ((img * COUT + co) * OH + oh) * OW;
#pragma unroll
            for (int ni = 0; ni < 4; ++ni) {
                const int ow = ni * 16 + ml;
                if (ow < OW) op[ow] = acc[mi][ni][r];
            }
        }
    }
}

// ---------- mid fallback: fp32-input kernel (WT only) ----------
__global__ void wt_transform_kernel(const float* __restrict__ Wsrc,
                                    unsigned short* __restrict__ WT) {
    int idx = blockIdx.x * 256 + threadIdx.x;
    int i   = idx & 7;
    int co  = (idx >> 3) & 255;
    int cgk = idx >> 11;
    int cg  = cgk & 15;
    int khw = cgk >> 4;
    int kh  = khw / 3, kw = khw - 3 * kh;
    int ci  = cg * 8 + i;
    WT[idx] = f2bf(Wsrc[co * (CIN * 9) + ci * 9 + kh * 3 + kw]);
}

__global__ __launch_bounds__(256, 2)
void conv_mfma_fp32_kernel(const float* __restrict__ In,
                           const unsigned short* __restrict__ WT,
                           float* __restrict__ Out) {
    __shared__ unsigned short Lin[66 * 32];

    const int oh   = blockIdx.x;
    const int img  = blockIdx.y;
    const int tid  = threadIdx.x;
    const int wave = tid >> 6;
    const int lane = tid & 63;
    const int q    = lane >> 4;
    const int ml   = lane & 15;
    const int co_base = wave * 64;

    f32x4 acc[4][4];
    const f32x4 zero = {0.f, 0.f, 0.f, 0.f};
#pragma unroll
    for (int a = 0; a < 4; ++a)
#pragma unroll
        for (int b = 0; b < 4; ++b) acc[a][b] = zero;

    if (tid < 32) ((unsigned int*)&Lin[64 * 32])[tid] = 0u;

    const int s_iw = tid & 63;
    const int s_cg = tid >> 6;
    const bf16x8* WTv = (const bf16x8*)WT;

    for (int kh = 0; kh < 3; ++kh) {
        const int ih = oh + kh;
        for (int cb = 0; cb < 4; ++cb) {
            const float* p = In + (((img * CIN + cb * 32 + s_cg * 8) * INH + ih) * INW + s_iw);
            u16x8 v;
#pragma unroll
            for (int i = 0; i < 8; ++i) v[i] = f2bf(p[i * (INH * INW)]);
            __syncthreads();
            *(u16x8*)&Lin[s_iw * 32 + ((s_cg ^ (s_iw & 3)) << 3)] = v;
            __syncthreads();

#pragma unroll
            for (int kw = 0; kw < 3; ++kw) {
                const int khw = kh * 3 + kw;
                bf16x8 wf[4], xf[4];
#pragma unroll
                for (int mi = 0; mi < 4; ++mi)
                    wf[mi] = WTv[(khw * 16 + cb * 4 + q) * 256 + co_base + mi * 16 + ml];
#pragma unroll
                for (int ni = 0; ni < 4; ++ni) {
                    const int row = ni * 16 + ml + kw;
                    xf[ni] = *(const bf16x8*)&Lin[row * 32 + ((q ^ (row & 3)) << 3)];
                }
#pragma unroll
                for (int mi = 0; mi < 4; ++mi)
#pragma unroll
                    for (int ni = 0; ni < 4; ++ni)
                        acc[mi][ni] = __builtin_amdgcn_mfma_f32_16x16x32_bf16(
                            wf[mi], xf[ni], acc[mi][ni], 0, 0, 0);
            }
        }
    }

#pragma unroll
    for (int mi = 0; mi < 4; ++mi) {
#pragma unroll
        for (int r = 0; r < 4; ++r) {
            const int co = co_base + mi * 16 + q * 4 + r;
            float* op = Out + ((img * COUT + co) * OH + oh) * OW;
#pragma unroll
            for (int ni = 0; ni < 4; ++ni) {
                const int ow = ni * 16 + ml;
                if (ow < OW) op[ow] = acc[mi][ni][r];
            }
        }
    }
}

// ---------- last-resort fallback ----------
__global__ void conv_naive_kernel(const float* __restrict__ In,
                                  const float* __restrict__ Wt,
                                  float* __restrict__ Out) {
    int idx = blockIdx.x * 256 + threadIdx.x;
    const int total = N_IMG * COUT * OH * OW;
    if (idx >= total) return;
    int ow = idx % OW; int t = idx / OW;
    int oh = t % OH;   t /= OH;
    int co = t % COUT; int img = t / COUT;
    float s = 0.f;
    for (int ci = 0; ci < CIN; ++ci)
#pragma unroll
        for (int kh = 0; kh < 3; ++kh)
#pragma unroll
            for (int kw = 0; kw < 3; ++kw)
                s += In[((img * CIN + ci) * INH + oh + kh) * INW + ow + kw] *
                     Wt[co * CIN * 9 + ci * 9 + kh * 3 + kw];
    Out[idx] = s;
}

extern "C" void kernel_launch(void* const* d_in, const int* in_sizes, int n_in,
                              void* d_out, int out_size, void* d_ws, size_t ws_size,
                              hipStream_t stream) {
    const float* In   = (const float*)d_in[0];
    const float* Wsrc = (const float*)d_in[1];
    float* Out        = (float*)d_out;

    const size_t WT_BYTES  = (size_t)9 * 16 * 256 * 8 * sizeof(unsigned short);      // 589824
    const size_t TIN_BYTES = (size_t)N_IMG * 4 * 64 * 2048 * sizeof(unsigned short); // 33554432

    if (ws_size >= WT_BYTES + TIN_BYTES) {
        unsigned short* WT  = (unsigned short*)d_ws;
        unsigned short* TIn = (unsigned short*)((char*)d_ws + WT_BYTES);
        transform_kernel<<<dim3(IN_BLOCKS + WT_BLOCKS), dim3(256), 0, stream>>>(In, Wsrc, TIn, WT);
        conv_mfma_bf16_kernel<<<dim3(OH * N_IMG), dim3(256), 0, stream>>>(TIn, WT, Out);
    } else if (ws_size >= WT_BYTES) {
        unsigned short* WT = (unsigned short*)d_ws;
        wt_transform_kernel<<<dim3(WT_BLOCKS), dim3(256), 0, stream>>>(Wsrc, WT);
        conv_mfma_fp32_kernel<<<dim3(OH, N_IMG), dim3(256), 0, stream>>>(In, WT, Out);
    } else {
        const int total = N_IMG * COUT * OH * OW;
        conv_naive_kernel<<<dim3((total + 255) / 256), dim3(256), 0, stream>>>(In, Wsrc, Out);
    }
}

// Round 12
// 236.682 us; speedup vs baseline: 1.1702x; 1.1702x over previous
//
#include <hip/hip_runtime.h>
#include <hip/hip_bf16.h>

#define N_IMG 32
#define CIN   128
#define INH   64
#define INW   64
#define COUT  256
#define OH    62
#define OW    62

#define IN_BLOCKS 2048               // 32 img x 4 cb x 16 ih-groups (4 rows each)
#define WT_BLOCKS (294912 / 256)     // 1152

typedef short          bf16x8 __attribute__((ext_vector_type(8)));
typedef unsigned short u16x8  __attribute__((ext_vector_type(8)));
typedef float          f32x4  __attribute__((ext_vector_type(4)));
typedef float          f32x2  __attribute__((ext_vector_type(2)));

__device__ __forceinline__ unsigned short f2bf(float x) {
    unsigned int u = __float_as_uint(x);
    u += 0x7fffu + ((u >> 16) & 1u);   // RNE
    return (unsigned short)(u >> 16);
}

__device__ __forceinline__ void gload_lds16(const void* g, void* l) {
    // global -> LDS DMA, 16 B per lane.
    // LDS dest: wave-uniform base, HW adds lane*16.
    // Global src: PER-LANE address (must include lane offset).
    __builtin_amdgcn_global_load_lds(
        (const __attribute__((address_space(1))) unsigned int*)g,
        (__attribute__((address_space(3))) unsigned int*)l, 16, 0, 0);
}

// Merged pre-pass: blocks [0,2048) transform input (4 ih rows each, ONE barrier),
// [2048, 2048+1152) transform weights.
// TIn layout: [img][cb(4)][ih(64)][chunk(256)][8] bf16; chunk c = (iw = c>>2,
// cg = (c&3) ^ ((iw>>1)&3)) — XOR swizzle baked into the GLOBAL layout so the
// linear global_load_lds DMA in conv lands pre-swizzled (rule #21).
// WT layout: [khw(9)][cg(16)][co(256)][i(8)] bf16, ci = cg*8 + i (A-frag order).
__global__ __launch_bounds__(256)
void transform_kernel(const float* __restrict__ In,
                      const float* __restrict__ Wsrc,
                      unsigned short* __restrict__ TIn,
                      unsigned short* __restrict__ WT) {
    if (blockIdx.x >= IN_BLOCKS) {      // ---- weight path (no barriers) ----
        int idx = (blockIdx.x - IN_BLOCKS) * 256 + threadIdx.x;   // < 294912
        int i   = idx & 7;
        int co  = (idx >> 3) & 255;
        int cgk = idx >> 11;            // khw*16 + cg
        int cg  = cgk & 15;
        int khw = cgk >> 4;             // 0..8
        int kh  = khw / 3, kw = khw - 3 * kh;
        int ci  = cg * 8 + i;
        WT[idx] = f2bf(Wsrc[co * (CIN * 9) + ci * 9 + kh * 3 + kw]);
        return;
    }
    // ---- input path: 4 rows staged at once, single barrier, coalesced both sides ----
    __shared__ float T[4][32][66];        // 33.8 KB; stride 66 keeps LDS 2-way max
    const int bid = blockIdx.x;           // img*64 + cb*16 + ihg
    const int ih0 = (bid & 15) * 4;
    const int cb  = (bid >> 4) & 3;
    const int img = bid >> 6;

    // load: thread t owns ci row r = t>>3, 8 floats at col (t&7)*8, for 4 ih rows
    {
        const int r  = threadIdx.x >> 3;
        const int c0 = (threadIdx.x & 7) * 8;
        const float* p = In + (((size_t)(img * CIN + cb * 32 + r)) * INH + ih0) * INW + c0;
#pragma unroll
        for (int j = 0; j < 4; ++j) {
            f32x4 a = *(const f32x4*)(p + j * INW);
            f32x4 b = *(const f32x4*)(p + j * INW + 4);
            *(f32x2*)&T[j][r][c0 + 0] = f32x2{a[0], a[1]};
            *(f32x2*)&T[j][r][c0 + 2] = f32x2{a[2], a[3]};
            *(f32x2*)&T[j][r][c0 + 4] = f32x2{b[0], b[1]};
            *(f32x2*)&T[j][r][c0 + 6] = f32x2{b[2], b[3]};
        }
    }
    __syncthreads();   // the only barrier

    // store: thread t emits chunk c=t for each of the 4 rows (16B, contiguous)
    const int c  = threadIdx.x;
    const int iw = c >> 2;
    const int cg = (c & 3) ^ ((iw >> 1) & 3);
    unsigned short* dst = TIn + ((size_t)((img * 4 + cb) * 64 + ih0) * 256 + c) * 8;
#pragma unroll
    for (int j = 0; j < 4; ++j) {
        u16x8 v;
#pragma unroll
        for (int i = 0; i < 8; ++i) v[i] = f2bf(T[j][cg * 8 + i][iw]);
        *(u16x8*)(dst + (size_t)j * 2048) = v;
    }
}

// Conv kernel: round-5 form verbatim — best measured across all structural
// variants (81.5 µs vs 85/83/103/108 for kw-pipeline / issue-order /
// barrier-free / fused-stage). One 256-thread block per (img, oh); wave w owns
// co in [64w, 64w+64). GEMM: D[m=co][n=ow] += sum_k W[co][k] * X[k][ow].
// 12 stages (kh x cb32), double-buffered global_load_lds staging,
// launch_bounds(256,4) = 4 blocks/CU (VGPR 64 + 64 AGPR = 128-reg cap),
// stage loop fully unrolled.
__global__ __launch_bounds__(256, 4)
void conv_mfma_bf16_kernel(const unsigned short* __restrict__ TIn,
                           const unsigned short* __restrict__ WT,
                           float* __restrict__ Out) {
    // [buf][66 rows][32 ushort]; rows 64-65 are permanent zero padding.
    __shared__ unsigned short Lin[2][2112];

    // Bijective XCD-chunked remap: 1984 = 8*248 -> XCD x gets images [4x, 4x+4).
    const int g   = blockIdx.x;
    const int f   = (g & 7) * 248 + (g >> 3);
    const int img = f / OH;
    const int oh  = f - img * OH;

    const int tid  = threadIdx.x;
    const int wave = tid >> 6;      // 0..3
    const int lane = tid & 63;
    const int q    = lane >> 4;     // quad 0..3
    const int ml   = lane & 15;
    const int co_base = wave * 64;

    const unsigned short* tin_base = TIn + (size_t)img * (4 * 64 * 2048);
    const bf16x8* WTv = (const bf16x8*)WT;
    const int wlane = q * 256 + co_base + ml;   // lane part of A-frag index

    // Per-lane LDS ushort offsets for B fragments (constant across stages).
    // Chunk slot for cg=q at row r is q ^ ((r>>1)&3): measured 0 bank conflicts.
    int xoff[3][4];
#pragma unroll
    for (int kw = 0; kw < 3; ++kw)
#pragma unroll
        for (int ni = 0; ni < 4; ++ni) {
            const int r = ni * 16 + ml + kw;
            xoff[kw][ni] = r * 32 + ((q ^ ((r >> 1) & 3)) << 3);
        }

    f32x4 acc[4][4];
    const f32x4 zero = {0.f, 0.f, 0.f, 0.f};
#pragma unroll
    for (int a = 0; a < 4; ++a)
#pragma unroll
        for (int b = 0; b < 4; ++b) acc[a][b] = zero;

    // Prologue: stage 0 into buf0 (one 16B DMA per thread) + zero pad rows.
    gload_lds16(tin_base + oh * 2048 + tid * 8, &Lin[0][wave * 512]);
    if (tid < 64) ((unsigned int*)&Lin[tid >> 5][64 * 32])[tid & 31] = 0u;
    __syncthreads();   // drains DMA (vmcnt 0) + pad writes

#pragma unroll
    for (int s = 0; s < 12; ++s) {
        const int cur = s & 1;
        if (s < 11) {   // issue next stage's DMA into the other buffer
            const int s1 = s + 1;
            const unsigned short* src =
                tin_base + ((s1 & 3) * 64 + oh + (s1 >> 2)) * 2048;
            gload_lds16(src + tid * 8, &Lin[cur ^ 1][wave * 512]);
        }
        const int kh = s >> 2, cb = s & 3;
#pragma unroll
        for (int kw = 0; kw < 3; ++kw) {
            const int khw = kh * 3 + kw;
            const bf16x8* wbase = WTv + (khw * 16 + cb * 4) * 256;   // uniform part
            bf16x8 wf[4], xf[4];
#pragma unroll
            for (int mi = 0; mi < 4; ++mi)
                wf[mi] = wbase[wlane + mi * 16];
#pragma unroll
            for (int ni = 0; ni < 4; ++ni)
                xf[ni] = *(const bf16x8*)&Lin[cur][xoff[kw][ni]];
#pragma unroll
            for (int mi = 0; mi < 4; ++mi)
#pragma unroll
                for (int ni = 0; ni < 4; ++ni)
                    acc[mi][ni] = __builtin_amdgcn_mfma_f32_16x16x32_bf16(
                        wf[mi], xf[ni], acc[mi][ni], 0, 0, 0);
        }
        __syncthreads();   // vmcnt(0): next buffer landed; readers of cur done
    }

    // Epilogue: C/D layout col=lane&15, row=q*4+r (verified 16x16x32 mapping).
#pragma unroll
    for (int mi = 0; mi < 4; ++mi) {
#pragma unroll
        for (int r = 0; r < 4; ++r) {
            const int co = co_base + mi * 16 + q * 4 + r;
            float* op = Out + ((img * COUT + co) * OH + oh) * OW;
#pragma unroll
            for (int ni = 0; ni < 4; ++ni) {
                const int ow = ni * 16 + ml;
                if (ow < OW) op[ow] = acc[mi][ni][r];
            }
        }
    }
}

// ---------- mid fallback: fp32-input kernel (WT only) ----------
__global__ void wt_transform_kernel(const float* __restrict__ Wsrc,
                                    unsigned short* __restrict__ WT) {
    int idx = blockIdx.x * 256 + threadIdx.x;
    int i   = idx & 7;
    int co  = (idx >> 3) & 255;
    int cgk = idx >> 11;
    int cg  = cgk & 15;
    int khw = cgk >> 4;
    int kh  = khw / 3, kw = khw - 3 * kh;
    int ci  = cg * 8 + i;
    WT[idx] = f2bf(Wsrc[co * (CIN * 9) + ci * 9 + kh * 3 + kw]);
}

__global__ __launch_bounds__(256, 2)
void conv_mfma_fp32_kernel(const float* __restrict__ In,
                           const unsigned short* __restrict__ WT,
                           float* __restrict__ Out) {
    __shared__ unsigned short Lin[66 * 32];

    const int oh   = blockIdx.x;
    const int img  = blockIdx.y;
    const int tid  = threadIdx.x;
    const int wave = tid >> 6;
    const int lane = tid & 63;
    const int q    = lane >> 4;
    const int ml   = lane & 15;
    const int co_base = wave * 64;

    f32x4 acc[4][4];
    const f32x4 zero = {0.f, 0.f, 0.f, 0.f};
#pragma unroll
    for (int a = 0; a < 4; ++a)
#pragma unroll
        for (int b = 0; b < 4; ++b) acc[a][b] = zero;

    if (tid < 32) ((unsigned int*)&Lin[64 * 32])[tid] = 0u;

    const int s_iw = tid & 63;
    const int s_cg = tid >> 6;
    const bf16x8* WTv = (const bf16x8*)WT;

    for (int kh = 0; kh < 3; ++kh) {
        const int ih = oh + kh;
        for (int cb = 0; cb < 4; ++cb) {
            const float* p = In + (((img * CIN + cb * 32 + s_cg * 8) * INH + ih) * INW + s_iw);
            u16x8 v;
#pragma unroll
            for (int i = 0; i < 8; ++i) v[i] = f2bf(p[i * (INH * INW)]);
            __syncthreads();
            *(u16x8*)&Lin[s_iw * 32 + ((s_cg ^ (s_iw & 3)) << 3)] = v;
            __syncthreads();

#pragma unroll
            for (int kw = 0; kw < 3; ++kw) {
                const int khw = kh * 3 + kw;
                bf16x8 wf[4], xf[4];
#pragma unroll
                for (int mi = 0; mi < 4; ++mi)
                    wf[mi] = WTv[(khw * 16 + cb * 4 + q) * 256 + co_base + mi * 16 + ml];
#pragma unroll
                for (int ni = 0; ni < 4; ++ni) {
                    const int row = ni * 16 + ml + kw;
                    xf[ni] = *(const bf16x8*)&Lin[row * 32 + ((q ^ (row & 3)) << 3)];
                }
#pragma unroll
                for (int mi = 0; mi < 4; ++mi)
#pragma unroll
                    for (int ni = 0; ni < 4; ++ni)
                        acc[mi][ni] = __builtin_amdgcn_mfma_f32_16x16x32_bf16(
                            wf[mi], xf[ni], acc[mi][ni], 0, 0, 0);
            }
        }
    }

#pragma unroll
    for (int mi = 0; mi < 4; ++mi) {
#pragma unroll
        for (int r = 0; r < 4; ++r) {
            const int co = co_base + mi * 16 + q * 4 + r;
            float* op = Out + ((img * COUT + co) * OH + oh) * OW;
#pragma unroll
            for (int ni = 0; ni < 4; ++ni) {
                const int ow = ni * 16 + ml;
                if (ow < OW) op[ow] = acc[mi][ni][r];
            }
        }
    }
}

// ---------- last-resort fallback ----------
__global__ void conv_naive_kernel(const float* __restrict__ In,
                                  const float* __restrict__ Wt,
                                  float* __restrict__ Out) {
    int idx = blockIdx.x * 256 + threadIdx.x;
    const int total = N_IMG * COUT * OH * OW;
    if (idx >= total) return;
    int ow = idx % OW; int t = idx / OW;
    int oh = t % OH;   t /= OH;
    int co = t % COUT; int img = t / COUT;
    float s = 0.f;
    for (int ci = 0; ci < CIN; ++ci)
#pragma unroll
        for (int kh = 0; kh < 3; ++kh)
#pragma unroll
            for (int kw = 0; kw < 3; ++kw)
                s += In[((img * CIN + ci) * INH + oh + kh) * INW + ow + kw] *
                     Wt[co * CIN * 9 + ci * 9 + kh * 3 + kw];
    Out[idx] = s;
}

extern "C" void kernel_launch(void* const* d_in, const int* in_sizes, int n_in,
                              void* d_out, int out_size, void* d_ws, size_t ws_size,
                              hipStream_t stream) {
    const float* In   = (const float*)d_in[0];
    const float* Wsrc = (const float*)d_in[1];
    float* Out        = (float*)d_out;

    const size_t WT_BYTES  = (size_t)9 * 16 * 256 * 8 * sizeof(unsigned short);      // 589824
    const size_t TIN_BYTES = (size_t)N_IMG * 4 * 64 * 2048 * sizeof(unsigned short); // 33554432

    if (ws_size >= WT_BYTES + TIN_BYTES) {
        unsigned short* WT  = (unsigned short*)d_ws;
        unsigned short* TIn = (unsigned short*)((char*)d_ws + WT_BYTES);
        transform_kernel<<<dim3(IN_BLOCKS + WT_BLOCKS), dim3(256), 0, stream>>>(In, Wsrc, TIn, WT);
        conv_mfma_bf16_kernel<<<dim3(OH * N_IMG), dim3(256), 0, stream>>>(TIn, WT, Out);
    } else if (ws_size >= WT_BYTES) {
        unsigned short* WT = (unsigned short*)d_ws;
        wt_transform_kernel<<<dim3(WT_BLOCKS), dim3(256), 0, stream>>>(Wsrc, WT);
        conv_mfma_fp32_kernel<<<dim3(OH, N_IMG), dim3(256), 0, stream>>>(In, WT, Out);
    } else {
        const int total = N_IMG * COUT * OH * OW;
        conv_naive_kernel<<<dim3((total + 255) / 256), dim3(256), 0, stream>>>(In, Wsrc, Out);
    }
}